// Round 3
// baseline (237.677 us; speedup 1.0000x reference)
//
#include <hip/hip_runtime.h>
#include <hip/hip_bf16.h>
#include <math.h>

#define N_NODES 100000
#define N_EDGES 1600000
#define IN_F 128
#define HID_F 128
#define OUT_F 64
#define K_TOT 384                          // 3 basis planes x 128
#define BST 392                            // basis LDS row stride (384 + 8 pad), bf16
#define MROWS 32                           // nodes per MFMA block (25 KB LDS -> 6 blk/CU)

// bucket sort parameters
#define BK_BITS 9
#define BK_SIZE 512                        // nodes per bucket
#define NBUCK ((N_NODES + BK_SIZE - 1) / BK_SIZE)   // 196
#define EPB 4096                           // edges per sort block
#define NBLK_SORT ((N_EDGES + EPB - 1) / EPB)       // 391
#define BCAP 10240                         // fixed bucket capacity (mean 8163 + ~23 sigma)
#define PCAP (BCAP + 7 * BK_SIZE)          // padded bucket capacity: 13824
// packed edge record: [31:23] local tgt (9b), [22:0] src (17b used)
#define PK_SRC_MASK 0x7fffffu
#define PAD8(d) (((d) + 7) & ~7)

typedef __attribute__((ext_vector_type(8))) short s8v;   // 8 bf16 (MFMA A/B frag)
typedef __attribute__((ext_vector_type(4))) short s4v;   // 4 bf16 (8 B LDS store)
typedef __attribute__((ext_vector_type(4))) float f4v;   // MFMA C/D frag
typedef __attribute__((ext_vector_type(2))) float f2v;   // cvt_pk_f32_fp8 result

__device__ __forceinline__ short f2bf(float f) {
    __hip_bfloat16 h = __float2bfloat16(f);
    return __builtin_bit_cast(short, h);
}

// ---------------------------------------------------------------------------
// Fold KAN weights into bf16 MFMA-B chunk layout; zero sentinel rows of
// h1/h2; seed per-bucket scatter cursors.
// ---------------------------------------------------------------------------
__global__ __launch_bounds__(256) void fold_weights_bf16(
    const float* __restrict__ w1, const float* __restrict__ c1,
    const float* __restrict__ w2, const float* __restrict__ c2,
    short* __restrict__ Wb1, short* __restrict__ Wb2,
    unsigned* __restrict__ h1d, unsigned* __restrict__ h2d,
    int* __restrict__ bcur)
{
    if (blockIdx.x == 0) {
        if (threadIdx.x < 32) h1d[(size_t)N_NODES * 32 + threadIdx.x] = 0;
        if (threadIdx.x < 16) h2d[(size_t)N_NODES * 16 + threadIdx.x] = 0;
        if (threadIdx.x < NBUCK) bcur[threadIdx.x] = threadIdx.x * BCAP;
    }
    int idx = blockIdx.x * 256 + threadIdx.x;
    if (idx < K_TOT * HID_F) {
        int k = idx >> 7, n = idx & 127;
        int p = k >> 7, f = k & 127;
        int si = f * HID_F + n;
        float v = (p == 0) ? (w1[si] + 0.1f * c1[si * 3])
                           : 0.1f * c1[si * 3 + p];
        Wb1[(((k >> 3) * HID_F) + n) * 8 + (k & 7)] = f2bf(v);
    } else {
        idx -= K_TOT * HID_F;
        if (idx < K_TOT * OUT_F) {
            int k = idx >> 6, n = idx & 63;
            int p = k >> 7, f = k & 127;
            int si = f * OUT_F + n;
            float v = (p == 0) ? (w2[si] + 0.1f * c2[si * 3])
                               : 0.1f * c2[si * 3 + p];
            Wb2[(((k >> 3) * OUT_F) + n) * 8 + (k & 7)] = f2bf(v);
        }
    }
}

// ---------------------------------------------------------------------------
// MERGED: bucket_scatter (blocks 0..NBLK_SORT-1) ∥ kan1 MFMA (remaining
// blocks).  kan1 path: 32 nodes/block, 25 KB LDS -> 6 blocks/CU (24 waves)
// for latency hiding on the x HBM reads.  Waves: wm=(wave&1)*16 rows,
// wn=(wave>>1)*64 cols, j=0..3.
// ---------------------------------------------------------------------------
__global__ __launch_bounds__(256) void scatter_kan1(
    const int* __restrict__ src, const int* __restrict__ tgt,
    int* __restrict__ bcur, unsigned* __restrict__ spk,
    const float* __restrict__ x, const short* __restrict__ Wb,
    const float* __restrict__ bias, unsigned* __restrict__ h1d)
{
    __shared__ __align__(16) char smem[MROWS * BST * 2];   // 25088 B
    const int tid = threadIdx.x;

    if (blockIdx.x < NBLK_SORT) {
        // ---- bucket scatter path ----
        int* h    = (int*)smem;
        int* base = h + NBUCK;
        int* tg   = base + NBUCK;               // EPB ints: 16 KB (total ~17.9 KB)
        for (int i = tid; i < NBUCK; i += 256) h[i] = 0;
        __syncthreads();
        int e0 = blockIdx.x * EPB;
        int n = min(EPB, N_EDGES - e0);
        for (int i = tid; i < n; i += 256) {
            int t = tgt[e0 + i];
            tg[i] = t;
            atomicAdd(&h[t >> BK_BITS], 1);
        }
        __syncthreads();
        for (int i = tid; i < NBUCK; i += 256) {
            int c = h[i];
            base[i] = c ? atomicAdd(&bcur[i], c) : 0;
            h[i] = 0;
        }
        __syncthreads();
        for (int i = tid; i < n; i += 256) {
            int t = tg[i];
            int b = t >> BK_BITS;
            int pos = base[b] + atomicAdd(&h[b], 1);
            spk[pos] = ((unsigned)(t - (b << BK_BITS)) << 23) | (unsigned)src[e0 + i];
        }
        return;
    }

    // ---- kan1 MFMA path (32 rows) ----
    short* sb = (short*)smem;
    const int lane = tid & 63;
    const int wave = tid >> 6;
    const int node0 = (blockIdx.x - NBLK_SORT) * MROWS;
    const int q = lane >> 4, r = lane & 15;

#pragma unroll
    for (int it = 0; it < 4; ++it) {
        int idx = tid + 256 * it;            // 1024 float4 groups
        int m = idx >> 5, c4 = (idx & 31) * 4;
        int gm = min(node0 + m, N_NODES - 1);
        float4 v = *(const float4*)(x + (size_t)gm * IN_F + c4);
        float vv[4] = {v.x, v.y, v.z, v.w};
        s4v p0, p1, p2;
#pragma unroll
        for (int t = 0; t < 4; ++t) {
            float e = vv[t], e2 = e * e, e3 = e2 * e;
            p0[t] = f2bf(e); p1[t] = f2bf(e2); p2[t] = f2bf(e3);
        }
        short* row = sb + m * BST + c4;
        *(s4v*)(row)       = p0;
        *(s4v*)(row + 128) = p1;
        *(s4v*)(row + 256) = p2;
    }
    __syncthreads();

    const int wm = (wave & 1) * 16;
    const int wn = (wave >> 1) * 64;

    f4v acc[4];
#pragma unroll
    for (int j = 0; j < 4; ++j)
        acc[j] = (f4v){0.f, 0.f, 0.f, 0.f};

    float bj[4];
#pragma unroll
    for (int j = 0; j < 4; ++j) bj[j] = bias[wn + j * 16 + r];

#pragma unroll
    for (int kb = 0; kb < 12; ++kb) {
        const int col = kb * 32 + q * 8;
        s8v afrag = *(const s8v*)(sb + (wm + r) * BST + col);
#pragma unroll
        for (int j = 0; j < 4; ++j) {
            const s8v b = *(const s8v*)(Wb + (((kb * 4 + q) * HID_F) + wn + j * 16 + r) * 8);
            acc[j] = __builtin_amdgcn_mfma_f32_16x16x32_bf16(afrag, b, acc[j], 0, 0, 0);
        }
    }

    const int dci = ((wn >> 6) << 4) + r;
#pragma unroll
    for (int e = 0; e < 4; ++e) {
        int grow = node0 + wm + q * 4 + e;
        if (grow < N_NODES) {
            float v0 = fmaxf(acc[0][e] + bj[0], 0.f);
            float v1 = fmaxf(acc[1][e] + bj[1], 0.f);
            float v2 = fmaxf(acc[2][e] + bj[2], 0.f);
            float v3 = fmaxf(acc[3][e] + bj[3], 0.f);
            int pk = __builtin_amdgcn_cvt_pk_fp8_f32(v0, v1, 0, false);
            pk = __builtin_amdgcn_cvt_pk_fp8_f32(v2, v3, pk, true);
            h1d[(size_t)grow * 32 + dci] = (unsigned)pk;
        }
    }
}

// ---------------------------------------------------------------------------
// csr_build, 512 threads: one node per thread (BK_SIZE == 512).  Per-bucket
// degree hist -> deg[]; padded prefix (bucket base b*PCAP) -> prow[]; fill
// padded CSR with LDS cursors; sentinel pad slots.  One spk pass.
// ---------------------------------------------------------------------------
__global__ __launch_bounds__(512) void csr_build(
    const int* __restrict__ bcur, const unsigned* __restrict__ spk,
    int* __restrict__ deg, int* __restrict__ prow, int* __restrict__ csr_pad)
{
    __shared__ int d[BK_SIZE];             // hist, then cursors
    __shared__ int pst[BK_SIZE];           // padded segment ends
    __shared__ int s[BK_SIZE];
    int tid = threadIdx.x;                 // 0..511
    int b = blockIdx.x;
    d[tid] = 0;
    __syncthreads();
    int e0 = b * BCAP, e1 = bcur[b];
    for (int i = e0 + tid; i < e1; i += 512)
        atomicAdd(&d[spk[i] >> 23], 1);
    __syncthreads();
    int nbase = b << BK_BITS;
    int node = nbase + tid;
    int a = d[tid];
    if (node < N_NODES) deg[node] = a;
    int pc = (node < N_NODES) ? PAD8(a) : 0;
    s[tid] = pc;
    __syncthreads();
    for (int o = 1; o < 512; o <<= 1) {
        int t = (tid >= o) ? s[tid - o] : 0;
        __syncthreads();
        s[tid] += t;
        __syncthreads();
    }
    int excl = s[tid] - pc;
    int base = b * PCAP + excl;
    if (node < N_NODES) prow[node] = base;
    __syncthreads();                       // d[] hist fully consumed
    d[tid] = base;
    pst[tid] = base + pc;
    __syncthreads();
    // fill
    for (int i = e0 + tid; i < e1; i += 512) {
        unsigned pk = spk[i];
        int pos = atomicAdd(&d[pk >> 23], 1);
        csr_pad[pos] = (int)(pk & PK_SRC_MASK);
    }
    __syncthreads();
    // sentinel pad slots (invalid nodes: pc==0 and no edges -> empty loop)
    {
        int kend = pst[tid];
        for (int k = d[tid]; k < kend; ++k) csr_pad[k] = N_NODES;
    }
}

// ---------------------------------------------------------------------------
// Gather-aggregate over 128 fp8 feats.  TWO nodes per wave; lane loads one
// dword (4 fp8) per message; cvt_pk decode; depth-4 chains.  Padded count
// from PAD8(deg).  Output a1 fp8, same permuted layout.
// ---------------------------------------------------------------------------
__global__ __launch_bounds__(256) void gather128(
    const unsigned* __restrict__ h1d, const int* __restrict__ prow,
    const int* __restrict__ deg, const int* __restrict__ csr_pad,
    unsigned* __restrict__ a1d)
{
    const int lane  = threadIdx.x & 63;
    const int wave  = threadIdx.x >> 6;
    const int hl    = lane & 31;
    const int half  = lane >> 5;
    const int hbase = half << 5;
    const int node  = blockIdx.x * 8 + wave * 2 + half;   // grid exact: 12500*8

    int p0 = prow[node];
    int cnt = PAD8(deg[node]);                            // multiple of 8
    int p1 = p0 + cnt;
    int cmax = max(cnt, __shfl_xor(cnt, 32));

    float acc[4][4];
#pragma unroll
    for (int t = 0; t < 4; ++t)
#pragma unroll
        for (int b = 0; b < 4; ++b) acc[t][b] = 0.f;

    for (int base = 0; base < cmax; base += 32) {
        int idx = max(min(p0 + base + hl, p1 - 1), 0);
        int sreg = csr_pad[idx];
        int lim = min(32, cmax - base);
        for (int j = 0; j < lim; j += 4) {
            if (base + j < cnt) {
                unsigned u[4];
#pragma unroll
                for (int t = 0; t < 4; ++t) {
                    int sj = __shfl(sreg, hbase + j + t);
                    u[t] = h1d[(size_t)sj * 32 + hl];
                }
#pragma unroll
                for (int t = 0; t < 4; ++t) {
                    f2v lo = __builtin_amdgcn_cvt_pk_f32_fp8(u[t], false);
                    f2v hi = __builtin_amdgcn_cvt_pk_f32_fp8(u[t], true);
                    acc[t][0] += lo.x; acc[t][1] += lo.y;
                    acc[t][2] += hi.x; acc[t][3] += hi.y;
                }
            }
        }
    }

    float s0 = (acc[0][0] + acc[1][0]) + (acc[2][0] + acc[3][0]);
    float s1 = (acc[0][1] + acc[1][1]) + (acc[2][1] + acc[3][1]);
    float s2 = (acc[0][2] + acc[1][2]) + (acc[2][2] + acc[3][2]);
    float s3 = (acc[0][3] + acc[1][3]) + (acc[2][3] + acc[3][3]);
    int pk = __builtin_amdgcn_cvt_pk_fp8_f32(s0, s1, 0, false);
    pk = __builtin_amdgcn_cvt_pk_fp8_f32(s2, s3, pk, true);
    a1d[(size_t)node * 32 + hl] = (unsigned)pk;
}

// ---------------------------------------------------------------------------
// KAN2 via MFMA bf16, 32 nodes/block (25 KB LDS -> 6 blocks/CU).  Staging
// decodes fp8 a1 (permuted), applies 1/deg, computes the bf16 basis into
// LDS (canonical order, 3 planes).  Waves: wm=(wave&1)*16, wn=(wave>>1)*32.
// Epilogue: fp8 h2 pair-packed (ushort (wn>>1)+r = feats wn+r, wn+16+r).
// ---------------------------------------------------------------------------
__global__ __launch_bounds__(256) void kan2_mfma(
    const unsigned* __restrict__ a1d, const int* __restrict__ deg,
    const short* __restrict__ Wb, const float* __restrict__ bias,
    unsigned short* __restrict__ h2s)
{
    __shared__ short sb[MROWS * BST];   // 25 KB
    const int tid  = threadIdx.x;
    const int lane = tid & 63;
    const int wave = tid >> 6;
    const int node0 = blockIdx.x * MROWS;
    const int q = lane >> 4, r = lane & 15;

    {
        int m = tid >> 3, cg = (tid & 7) * 4;          // 32 rows x 8 uint4 groups
        int gm = min(node0 + m, N_NODES - 1);
        float di = 1.0f / fmaxf((float)deg[gm], 1.0f);
        uint4 u4 = *(const uint4*)(a1d + (size_t)gm * 32 + cg);
        unsigned uw[4] = {u4.x, u4.y, u4.z, u4.w};
        float xv[4][4];
#pragma unroll
        for (int j = 0; j < 4; ++j) {
            f2v lo = __builtin_amdgcn_cvt_pk_f32_fp8(uw[j], false);
            f2v hi = __builtin_amdgcn_cvt_pk_f32_fp8(uw[j], true);
            xv[j][0] = lo.x * di; xv[j][1] = lo.y * di;
            xv[j][2] = hi.x * di; xv[j][3] = hi.y * di;
        }
        int fb = ((cg >> 4) << 6) + (cg & 15);
#pragma unroll
        for (int b = 0; b < 4; ++b) {
            s4v p0, p1, p2;
#pragma unroll
            for (int j = 0; j < 4; ++j) {
                float e = xv[j][b], e2 = e * e, e3 = e2 * e;
                p0[j] = f2bf(e); p1[j] = f2bf(e2); p2[j] = f2bf(e3);
            }
            short* row = sb + m * BST + fb + 16 * b;
            *(s4v*)(row)       = p0;
            *(s4v*)(row + 128) = p1;
            *(s4v*)(row + 256) = p2;
        }
    }
    __syncthreads();

    const int wm = (wave & 1) * 16;
    const int wn = (wave >> 1) * 32;

    f4v acc[2];
#pragma unroll
    for (int j = 0; j < 2; ++j)
        acc[j] = (f4v){0.f, 0.f, 0.f, 0.f};

    float bj[2];
#pragma unroll
    for (int j = 0; j < 2; ++j) bj[j] = bias[wn + j * 16 + r];

#pragma unroll
    for (int kb = 0; kb < 12; ++kb) {
        const int col = kb * 32 + q * 8;
        s8v afrag = *(const s8v*)(sb + (wm + r) * BST + col);
#pragma unroll
        for (int j = 0; j < 2; ++j) {
            const s8v b = *(const s8v*)(Wb + (((kb * 4 + q) * OUT_F) + wn + j * 16 + r) * 8);
            acc[j] = __builtin_amdgcn_mfma_f32_16x16x32_bf16(afrag, b, acc[j], 0, 0, 0);
        }
    }

    const int sslot = (wn >> 1) + r;           // ushort slot in h2 row
#pragma unroll
    for (int e = 0; e < 4; ++e) {
        int grow = node0 + wm + q * 4 + e;
        if (grow < N_NODES) {
            float vlo = acc[0][e] + bj[0];
            float vhi = acc[1][e] + bj[1];
            int pk = __builtin_amdgcn_cvt_pk_fp8_f32(vlo, vhi, 0, false);
            h2s[(size_t)grow * 32 + sslot] = (unsigned short)(pk & 0xffff);
        }
    }
}

// ---------------------------------------------------------------------------
// Gather-aggregate over 64 fp8 feats + 1/deg + log_softmax.
// TWO nodes per wave; lane hl loads ushort (2 fp8 feats):
//   f_lo = 32*(hl>>4) + (hl&15), f_hi = f_lo + 16.
// ---------------------------------------------------------------------------
__global__ __launch_bounds__(256) void gather64_lsm(
    const unsigned short* __restrict__ h2s, const int* __restrict__ deg,
    const int* __restrict__ prow, const int* __restrict__ csr_pad,
    float* __restrict__ out)
{
    const int lane = threadIdx.x & 63;
    const int wave = threadIdx.x >> 6;
    const int hl   = lane & 31;
    const int half = lane >> 5;
    const int node = blockIdx.x * 8 + wave * 2 + half;   // grid exact: 12500*8

    int p0 = prow[node];
    int degr = deg[node];
    int cnt = PAD8(degr);
    int p1 = p0 + cnt;
    int cmax = max(cnt, __shfl_xor(cnt, 32));

    float alo[8], ahi[8];
#pragma unroll
    for (int t = 0; t < 8; ++t) { alo[t] = 0.f; ahi[t] = 0.f; }

    for (int base = 0; base < cmax; base += 32) {
        int idx = max(min(p0 + base + hl, p1 - 1), 0);
        int sreg = csr_pad[idx];
        int lim = min(32, cmax - base);
        for (int j = 0; j < lim; j += 8) {
            if (base + j < cnt) {
                int u[8];
#pragma unroll
                for (int t = 0; t < 8; ++t) {
                    int sj = __shfl(sreg, (half << 5) + j + t);
                    u[t] = (int)h2s[(size_t)sj * 32 + hl];
                }
#pragma unroll
                for (int t = 0; t < 8; ++t) {
                    alo[t] += __builtin_amdgcn_cvt_f32_fp8(u[t], 0);
                    ahi[t] += __builtin_amdgcn_cvt_f32_fp8(u[t], 1);
                }
            }
        }
    }
    float slo = ((alo[0] + alo[1]) + (alo[2] + alo[3])) + ((alo[4] + alo[5]) + (alo[6] + alo[7]));
    float shi = ((ahi[0] + ahi[1]) + (ahi[2] + ahi[3])) + ((ahi[4] + ahi[5]) + (ahi[6] + ahi[7]));

    float di = 1.0f / fmaxf((float)degr, 1.0f);
    float vlo = slo * di, vhi = shi * di;

    float m = fmaxf(vlo, vhi);
#pragma unroll
    for (int off = 16; off >= 1; off >>= 1)
        m = fmaxf(m, __shfl_xor(m, off));     // stays within the 32-lane half
    float e = expf(vlo - m) + expf(vhi - m);
#pragma unroll
    for (int off = 16; off >= 1; off >>= 1)
        e += __shfl_xor(e, off);
    float ls = logf(e);

    const int f_lo = ((hl >> 4) << 5) + (hl & 15);
    out[(size_t)node * OUT_F + f_lo]      = vlo - m - ls;
    out[(size_t)node * OUT_F + f_lo + 16] = vhi - m - ls;
}

// ---------------------------------------------------------------------------
extern "C" void kernel_launch(void* const* d_in, const int* in_sizes, int n_in,
                              void* d_out, int out_size, void* d_ws, size_t ws_size,
                              hipStream_t stream)
{
    const float* x  = (const float*)d_in[0];
    const int*   ei = (const int*)d_in[1];
    const float* w1 = (const float*)d_in[2];
    const float* b1 = (const float*)d_in[3];
    const float* c1 = (const float*)d_in[4];
    const float* w2 = (const float*)d_in[5];
    const float* b2 = (const float*)d_in[6];
    const float* c2 = (const float*)d_in[7];
    float* out = (float*)d_out;

    const int* src = ei;            // edge_index[0]
    const int* tgt = ei + N_EDGES;  // edge_index[1]

    char* ws = (char*)d_ws;
    size_t off = 0;
    auto carve = [&](size_t bytes) -> void* {
        void* p = ws + off;
        off = (off + bytes + 255) & ~(size_t)255;
        return p;
    };
    short*    Wb1       = (short*)carve((size_t)K_TOT * HID_F * 2);
    short*    Wb2       = (short*)carve((size_t)K_TOT * OUT_F * 2);
    int*      deg       = (int*)carve((size_t)N_NODES * 4);
    int*      prow      = (int*)carve((size_t)N_NODES * 4);
    int*      bcur      = (int*)carve((size_t)NBUCK * 4);
    unsigned* spk       = (unsigned*)carve((size_t)NBUCK * BCAP * 4);
    int*      csr_pad   = (int*)carve((size_t)NBUCK * PCAP * 4);
    unsigned* h1d       = (unsigned*)carve(((size_t)N_NODES + 1) * 128);  // fp8, permuted
    unsigned* a1d       = (unsigned*)carve((size_t)N_NODES * 128);        // fp8, permuted
    unsigned short* h2s = (unsigned short*)carve(((size_t)N_NODES + 1) * 64); // fp8 pairs

    const int grid_mm = (N_NODES + MROWS - 1) / MROWS;   // 3125

    // --- weights + sentinel rows + bucket cursor init ------------------------
    fold_weights_bf16<<<(K_TOT * HID_F + K_TOT * OUT_F + 255) / 256, 256, 0, stream>>>(
        w1, c1, w2, c2, Wb1, Wb2, h1d, (unsigned*)h2s, bcur);

    // --- bucket scatter ∥ layer 1 (block-specialized, independent) -----------
    scatter_kan1<<<NBLK_SORT + grid_mm, 256, 0, stream>>>(
        src, tgt, bcur, spk, x, Wb1, b1, h1d);

    // --- CSR finalize (512 threads: one node per thread) ---------------------
    csr_build<<<NBUCK, 512, 0, stream>>>(bcur, spk, deg, prow, csr_pad);

    // --- aggregate 1 (gather, fp8 rows, 2 nodes/wave) ------------------------
    gather128<<<(N_NODES + 7) / 8, 256, 0, stream>>>(h1d, prow, deg, csr_pad, a1d);

    // --- layer 2 (fp8 in, fp8 out) -------------------------------------------
    kan2_mfma<<<grid_mm, 256, 0, stream>>>(a1d, deg, Wb2, b2, h2s);

    // --- aggregate 2 + log_softmax (fused, 2 nodes/wave, fp8) ----------------
    gather64_lsm<<<(N_NODES + 7) / 8, 256, 0, stream>>>(
        h2s, deg, prow, csr_pad, out);
}

// Round 5
// 230.900 us; speedup vs baseline: 1.0294x; 1.0294x over previous
//
#include <hip/hip_runtime.h>
#include <hip/hip_bf16.h>
#include <math.h>

#define N_NODES 100000
#define N_EDGES 1600000
#define IN_F 128
#define HID_F 128
#define OUT_F 64
#define K_TOT 384                          // 3 basis planes x 128
#define BST 392                            // basis LDS row stride (384 + 8 pad), bf16

// bucket sort parameters (256-node buckets: 2x parallelism in csr build)
#define BK_BITS 8
#define BK_SIZE 256                        // nodes per bucket
#define NBUCK ((N_NODES + BK_SIZE - 1) / BK_SIZE)   // 391
#define EPB 4096                           // edges per sort block
#define NBLK_SORT ((N_EDGES + EPB - 1) / EPB)       // 391
#define BCAP 5120                          // bucket capacity (mean 4096 + 16 sigma)
#define PCAP (BCAP + 7 * BK_SIZE)          // padded bucket capacity: 6912
// packed edge record: [31:24] local tgt (8b), [23:0] src (17b used)
#define PK_SRC_MASK 0xffffffu
#define PAD8(d) (((d) + 7) & ~7)

// kan1 block split across the two boundary kernels (64 nodes per block)
#define K1T ((N_NODES + 63) / 64)          // 1563
#define K1A 781                            // kan1 blocks riding with scatter
#define K1B (K1T - K1A)                    // 782 riding with csr build

typedef __attribute__((ext_vector_type(8))) short s8v;   // 8 bf16 (MFMA A/B frag)
typedef __attribute__((ext_vector_type(4))) short s4v;   // 4 bf16 (8 B LDS store)
typedef __attribute__((ext_vector_type(4))) float f4v;   // MFMA C/D frag
typedef __attribute__((ext_vector_type(2))) float f2v;   // cvt_pk_f32_fp8 result

__device__ __forceinline__ short f2bf(float f) {
    __hip_bfloat16 h = __float2bfloat16(f);
    return __builtin_bit_cast(short, h);
}

// ---------------------------------------------------------------------------
// Fold KAN weights into bf16 MFMA-B chunk layout; zero sentinel rows of
// h1/h2; seed per-bucket scatter cursors (NBUCK=391 > 256: loop!).
// ---------------------------------------------------------------------------
__global__ __launch_bounds__(256) void fold_weights_bf16(
    const float* __restrict__ w1, const float* __restrict__ c1,
    const float* __restrict__ w2, const float* __restrict__ c2,
    short* __restrict__ Wb1, short* __restrict__ Wb2,
    unsigned* __restrict__ h1d, unsigned* __restrict__ h2d,
    int* __restrict__ bcur)
{
    if (blockIdx.x == 0) {
        if (threadIdx.x < 32) h1d[(size_t)N_NODES * 32 + threadIdx.x] = 0;
        if (threadIdx.x < 16) h2d[(size_t)N_NODES * 16 + threadIdx.x] = 0;
        for (int i = threadIdx.x; i < NBUCK; i += 256) bcur[i] = i * BCAP;
    }
    int idx = blockIdx.x * 256 + threadIdx.x;
    if (idx < K_TOT * HID_F) {
        int k = idx >> 7, n = idx & 127;
        int p = k >> 7, f = k & 127;
        int si = f * HID_F + n;
        float v = (p == 0) ? (w1[si] + 0.1f * c1[si * 3])
                           : 0.1f * c1[si * 3 + p];
        Wb1[(((k >> 3) * HID_F) + n) * 8 + (k & 7)] = f2bf(v);
    } else {
        idx -= K_TOT * HID_F;
        if (idx < K_TOT * OUT_F) {
            int k = idx >> 6, n = idx & 63;
            int p = k >> 7, f = k & 127;
            int si = f * OUT_F + n;
            float v = (p == 0) ? (w2[si] + 0.1f * c2[si * 3])
                               : 0.1f * c2[si * 3 + p];
            Wb2[(((k >> 3) * OUT_F) + n) * 8 + (k & 7)] = f2bf(v);
        }
    }
}

// ---------------------------------------------------------------------------
// kan1 MFMA body (64 nodes/block, 50 KB LDS) — shared by both boundary
// kernels.  Round-2 proven code: wm=(wave&1)*32, wn=(wave>>1)*64.
// ---------------------------------------------------------------------------
__device__ __forceinline__ void kan1_body(
    short* sb, int node0,
    const float* __restrict__ x, const short* __restrict__ Wb,
    const float* __restrict__ bias, unsigned* __restrict__ h1d)
{
    const int tid  = threadIdx.x;
    const int lane = tid & 63;
    const int wave = tid >> 6;
    const int q = lane >> 4, r = lane & 15;

#pragma unroll
    for (int it = 0; it < 8; ++it) {
        int idx = tid + 256 * it;            // 2048 float4 groups
        int m = idx >> 5, c4 = (idx & 31) * 4;
        int gm = min(node0 + m, N_NODES - 1);
        float4 v = *(const float4*)(x + (size_t)gm * IN_F + c4);
        float vv[4] = {v.x, v.y, v.z, v.w};
        s4v p0, p1, p2;
#pragma unroll
        for (int t = 0; t < 4; ++t) {
            float e = vv[t], e2 = e * e, e3 = e2 * e;
            p0[t] = f2bf(e); p1[t] = f2bf(e2); p2[t] = f2bf(e3);
        }
        short* row = sb + m * BST + c4;
        *(s4v*)(row)       = p0;
        *(s4v*)(row + 128) = p1;
        *(s4v*)(row + 256) = p2;
    }
    __syncthreads();

    const int wm = (wave & 1) * 32;
    const int wn = (wave >> 1) * 64;

    f4v acc[2][4];
#pragma unroll
    for (int i = 0; i < 2; ++i)
#pragma unroll
        for (int j = 0; j < 4; ++j)
            acc[i][j] = (f4v){0.f, 0.f, 0.f, 0.f};

    float bj[4];
#pragma unroll
    for (int j = 0; j < 4; ++j) bj[j] = bias[wn + j * 16 + r];

#pragma unroll
    for (int kb = 0; kb < 12; ++kb) {
        const int col = kb * 32 + q * 8;
        s8v afrag[2];
#pragma unroll
        for (int i = 0; i < 2; ++i)
            afrag[i] = *(const s8v*)(sb + (wm + i * 16 + r) * BST + col);
#pragma unroll
        for (int j = 0; j < 4; ++j) {
            const s8v b = *(const s8v*)(Wb + (((kb * 4 + q) * HID_F) + wn + j * 16 + r) * 8);
            acc[0][j] = __builtin_amdgcn_mfma_f32_16x16x32_bf16(afrag[0], b, acc[0][j], 0, 0, 0);
            acc[1][j] = __builtin_amdgcn_mfma_f32_16x16x32_bf16(afrag[1], b, acc[1][j], 0, 0, 0);
        }
    }

    const int dci = ((wn >> 6) << 4) + r;
#pragma unroll
    for (int i = 0; i < 2; ++i)
#pragma unroll
        for (int e = 0; e < 4; ++e) {
            int grow = node0 + wm + i * 16 + q * 4 + e;
            if (grow < N_NODES) {
                float v0 = fmaxf(acc[i][0][e] + bj[0], 0.f);
                float v1 = fmaxf(acc[i][1][e] + bj[1], 0.f);
                float v2 = fmaxf(acc[i][2][e] + bj[2], 0.f);
                float v3 = fmaxf(acc[i][3][e] + bj[3], 0.f);
                int pk = __builtin_amdgcn_cvt_pk_fp8_f32(v0, v1, 0, false);
                pk = __builtin_amdgcn_cvt_pk_fp8_f32(v2, v3, pk, true);
                h1d[(size_t)grow * 32 + dci] = (unsigned)pk;
            }
        }
}

// ---------------------------------------------------------------------------
// Kernel A: bucket_scatter (blocks 0..NBLK_SORT-1) ∥ kan1 part A.
// ---------------------------------------------------------------------------
__global__ __launch_bounds__(256) void scatter_kan1(
    const int* __restrict__ src, const int* __restrict__ tgt,
    int* __restrict__ bcur, unsigned* __restrict__ spk,
    const float* __restrict__ x, const short* __restrict__ Wb,
    const float* __restrict__ bias, unsigned* __restrict__ h1d)
{
    __shared__ __align__(16) char smem[64 * BST * 2];   // 50176 B
    const int tid = threadIdx.x;

    if (blockIdx.x < NBLK_SORT) {
        // ---- bucket scatter path ----
        int* h    = (int*)smem;
        int* base = h + NBUCK;
        int* tg   = base + NBUCK;               // EPB ints; total ~19.5 KB
        for (int i = tid; i < NBUCK; i += 256) h[i] = 0;
        __syncthreads();
        int e0 = blockIdx.x * EPB;
        int n = min(EPB, N_EDGES - e0);
        for (int i = tid; i < n; i += 256) {
            int t = tgt[e0 + i];
            tg[i] = t;
            atomicAdd(&h[t >> BK_BITS], 1);
        }
        __syncthreads();
        for (int i = tid; i < NBUCK; i += 256) {
            int c = h[i];
            base[i] = c ? atomicAdd(&bcur[i], c) : 0;
            h[i] = 0;
        }
        __syncthreads();
        for (int i = tid; i < n; i += 256) {
            int t = tg[i];
            int b = t >> BK_BITS;
            int pos = base[b] + atomicAdd(&h[b], 1);
            spk[pos] = ((unsigned)(t - (b << BK_BITS)) << 24) | (unsigned)src[e0 + i];
        }
        return;
    }

    kan1_body((short*)smem, ((int)blockIdx.x - NBLK_SORT) * 64, x, Wb, bias, h1d);
}

// ---------------------------------------------------------------------------
// Kernel B: csr build (blocks 0..NBUCK-1, 256 thr = 1 node/thread) ∥ kan1
// part B.  csr: per-bucket degree hist -> deg[]; padded prefix -> prow[];
// fill padded CSR with LDS cursors; sentinel pad slots.
// ---------------------------------------------------------------------------
__global__ __launch_bounds__(256) void csr_kan1(
    const int* __restrict__ bcur, const unsigned* __restrict__ spk,
    int* __restrict__ deg, int* __restrict__ prow, int* __restrict__ csr_pad,
    const float* __restrict__ x, const short* __restrict__ Wb,
    const float* __restrict__ bias, unsigned* __restrict__ h1d)
{
    __shared__ __align__(16) char smem[64 * BST * 2];   // 50176 B (union)
    const int tid = threadIdx.x;

    if (blockIdx.x < NBUCK) {
        int* d   = (int*)smem;                 // hist, then cursors
        int* pst = d + BK_SIZE;                // padded segment ends
        int* s   = pst + BK_SIZE;              // scan
        int b = blockIdx.x;
        d[tid] = 0;
        __syncthreads();
        int e0 = b * BCAP, e1 = bcur[b];
        for (int i = e0 + tid; i < e1; i += 256)
            atomicAdd(&d[spk[i] >> 24], 1);
        __syncthreads();
        int nbase = b << BK_BITS;
        int node = nbase + tid;
        int a = d[tid];
        if (node < N_NODES) deg[node] = a;
        int pc = (node < N_NODES) ? PAD8(a) : 0;
        s[tid] = pc;
        __syncthreads();
        for (int o = 1; o < 256; o <<= 1) {
            int t = (tid >= o) ? s[tid - o] : 0;
            __syncthreads();
            s[tid] += t;
            __syncthreads();
        }
        int excl = s[tid] - pc;
        int base = b * PCAP + excl;
        if (node < N_NODES) prow[node] = base;
        __syncthreads();                       // hist consumed
        d[tid] = base;
        pst[tid] = base + pc;
        __syncthreads();
        // fill
        for (int i = e0 + tid; i < e1; i += 256) {
            unsigned pk = spk[i];
            int pos = atomicAdd(&d[pk >> 24], 1);
            csr_pad[pos] = (int)(pk & PK_SRC_MASK);
        }
        __syncthreads();
        // sentinel pad slots
        {
            int kend = pst[tid];
            for (int k = d[tid]; k < kend; ++k) csr_pad[k] = N_NODES;
        }
        return;
    }

    kan1_body((short*)smem, (K1A + (int)blockIdx.x - NBUCK) * 64, x, Wb, bias, h1d);
}

// ---------------------------------------------------------------------------
// Gather-aggregate over 128 fp8 feats.  TWO nodes per wave; lane loads one
// dword (4 fp8) per message; cvt_pk decode; depth-4 chains.  Padded count
// from PAD8(deg).  Output a1 fp8, same permuted layout.
// ---------------------------------------------------------------------------
__global__ __launch_bounds__(256) void gather128(
    const unsigned* __restrict__ h1d, const int* __restrict__ prow,
    const int* __restrict__ deg, const int* __restrict__ csr_pad,
    unsigned* __restrict__ a1d)
{
    const int lane  = threadIdx.x & 63;
    const int wave  = threadIdx.x >> 6;
    const int hl    = lane & 31;
    const int half  = lane >> 5;
    const int hbase = half << 5;
    const int node  = blockIdx.x * 8 + wave * 2 + half;   // grid exact: 12500*8

    int p0 = prow[node];
    int cnt = PAD8(deg[node]);                            // multiple of 8
    int p1 = p0 + cnt;
    int cmax = max(cnt, __shfl_xor(cnt, 32));

    float acc[4][4];
#pragma unroll
    for (int t = 0; t < 4; ++t)
#pragma unroll
        for (int b = 0; b < 4; ++b) acc[t][b] = 0.f;

    for (int base = 0; base < cmax; base += 32) {
        int idx = max(min(p0 + base + hl, p1 - 1), 0);
        int sreg = csr_pad[idx];
        int lim = min(32, cmax - base);
        for (int j = 0; j < lim; j += 4) {
            if (base + j < cnt) {
                unsigned u[4];
#pragma unroll
                for (int t = 0; t < 4; ++t) {
                    int sj = __shfl(sreg, hbase + j + t);
                    u[t] = h1d[(size_t)sj * 32 + hl];
                }
#pragma unroll
                for (int t = 0; t < 4; ++t) {
                    f2v lo = __builtin_amdgcn_cvt_pk_f32_fp8(u[t], false);
                    f2v hi = __builtin_amdgcn_cvt_pk_f32_fp8(u[t], true);
                    acc[t][0] += lo.x; acc[t][1] += lo.y;
                    acc[t][2] += hi.x; acc[t][3] += hi.y;
                }
            }
        }
    }

    float s0 = (acc[0][0] + acc[1][0]) + (acc[2][0] + acc[3][0]);
    float s1 = (acc[0][1] + acc[1][1]) + (acc[2][1] + acc[3][1]);
    float s2 = (acc[0][2] + acc[1][2]) + (acc[2][2] + acc[3][2]);
    float s3 = (acc[0][3] + acc[1][3]) + (acc[2][3] + acc[3][3]);
    int pk = __builtin_amdgcn_cvt_pk_fp8_f32(s0, s1, 0, false);
    pk = __builtin_amdgcn_cvt_pk_fp8_f32(s2, s3, pk, true);
    a1d[(size_t)node * 32 + hl] = (unsigned)pk;
}

// ---------------------------------------------------------------------------
// KAN2 via MFMA bf16 (64 nodes/block, round-2 proven).  Staging decodes fp8
// a1 (permuted), applies 1/deg, computes the bf16 basis into LDS (canonical
// order, 3 planes).  Epilogue: fp8 h2 pair-packed.
// ---------------------------------------------------------------------------
__global__ __launch_bounds__(256) void kan2_mfma(
    const unsigned* __restrict__ a1d, const int* __restrict__ deg,
    const short* __restrict__ Wb, const float* __restrict__ bias,
    unsigned short* __restrict__ h2s)
{
    __shared__ short sb[64 * BST];   // 50 KB
    const int tid  = threadIdx.x;
    const int lane = tid & 63;
    const int wave = tid >> 6;
    const int node0 = blockIdx.x * 64;
    const int q = lane >> 4, r = lane & 15;

#pragma unroll
    for (int gi = 0; gi < 2; ++gi) {
        int g = tid + 256 * gi;
        int m = g >> 3, cg = (g & 7) * 4;
        int gm = min(node0 + m, N_NODES - 1);
        float di = 1.0f / fmaxf((float)deg[gm], 1.0f);
        uint4 u4 = *(const uint4*)(a1d + (size_t)gm * 32 + cg);
        unsigned uw[4] = {u4.x, u4.y, u4.z, u4.w};
        float xv[4][4];
#pragma unroll
        for (int j = 0; j < 4; ++j) {
            f2v lo = __builtin_amdgcn_cvt_pk_f32_fp8(uw[j], false);
            f2v hi = __builtin_amdgcn_cvt_pk_f32_fp8(uw[j], true);
            xv[j][0] = lo.x * di; xv[j][1] = lo.y * di;
            xv[j][2] = hi.x * di; xv[j][3] = hi.y * di;
        }
        int fb = ((cg >> 4) << 6) + (cg & 15);
#pragma unroll
        for (int b = 0; b < 4; ++b) {
            s4v p0, p1, p2;
#pragma unroll
            for (int j = 0; j < 4; ++j) {
                float e = xv[j][b], e2 = e * e, e3 = e2 * e;
                p0[j] = f2bf(e); p1[j] = f2bf(e2); p2[j] = f2bf(e3);
            }
            short* row = sb + m * BST + fb + 16 * b;
            *(s4v*)(row)       = p0;
            *(s4v*)(row + 128) = p1;
            *(s4v*)(row + 256) = p2;
        }
    }
    __syncthreads();

    const int wm = (wave & 1) * 32;
    const int wn = (wave >> 1) * 32;

    f4v acc[2][2];
#pragma unroll
    for (int i = 0; i < 2; ++i)
#pragma unroll
        for (int j = 0; j < 2; ++j)
            acc[i][j] = (f4v){0.f, 0.f, 0.f, 0.f};

    float bj[2];
#pragma unroll
    for (int j = 0; j < 2; ++j) bj[j] = bias[wn + j * 16 + r];

#pragma unroll
    for (int kb = 0; kb < 12; ++kb) {
        const int col = kb * 32 + q * 8;
        s8v afrag[2];
#pragma unroll
        for (int i = 0; i < 2; ++i)
            afrag[i] = *(const s8v*)(sb + (wm + i * 16 + r) * BST + col);
#pragma unroll
        for (int j = 0; j < 2; ++j) {
            const s8v b = *(const s8v*)(Wb + (((kb * 4 + q) * OUT_F) + wn + j * 16 + r) * 8);
            acc[0][j] = __builtin_amdgcn_mfma_f32_16x16x32_bf16(afrag[0], b, acc[0][j], 0, 0, 0);
            acc[1][j] = __builtin_amdgcn_mfma_f32_16x16x32_bf16(afrag[1], b, acc[1][j], 0, 0, 0);
        }
    }

    const int sslot = (wn >> 1) + r;           // ushort slot in h2 row
#pragma unroll
    for (int i = 0; i < 2; ++i)
#pragma unroll
        for (int e = 0; e < 4; ++e) {
            int grow = node0 + wm + i * 16 + q * 4 + e;
            if (grow < N_NODES) {
                float vlo = acc[i][0][e] + bj[0];
                float vhi = acc[i][1][e] + bj[1];
                int pk = __builtin_amdgcn_cvt_pk_fp8_f32(vlo, vhi, 0, false);
                h2s[(size_t)grow * 32 + sslot] = (unsigned short)(pk & 0xffff);
            }
        }
}

// ---------------------------------------------------------------------------
// Gather-aggregate over 64 fp8 feats + 1/deg + log_softmax.
// TWO nodes per wave; lane hl loads ushort (2 fp8 feats):
//   f_lo = 32*(hl>>4) + (hl&15), f_hi = f_lo + 16.
// ---------------------------------------------------------------------------
__global__ __launch_bounds__(256) void gather64_lsm(
    const unsigned short* __restrict__ h2s, const int* __restrict__ deg,
    const int* __restrict__ prow, const int* __restrict__ csr_pad,
    float* __restrict__ out)
{
    const int lane = threadIdx.x & 63;
    const int wave = threadIdx.x >> 6;
    const int hl   = lane & 31;
    const int half = lane >> 5;
    const int node = blockIdx.x * 8 + wave * 2 + half;   // grid exact: 12500*8

    int p0 = prow[node];
    int degr = deg[node];
    int cnt = PAD8(degr);
    int p1 = p0 + cnt;
    int cmax = max(cnt, __shfl_xor(cnt, 32));

    float alo[8], ahi[8];
#pragma unroll
    for (int t = 0; t < 8; ++t) { alo[t] = 0.f; ahi[t] = 0.f; }

    for (int base = 0; base < cmax; base += 32) {
        int idx = max(min(p0 + base + hl, p1 - 1), 0);
        int sreg = csr_pad[idx];
        int lim = min(32, cmax - base);
        for (int j = 0; j < lim; j += 8) {
            if (base + j < cnt) {
                int u[8];
#pragma unroll
                for (int t = 0; t < 8; ++t) {
                    int sj = __shfl(sreg, (half << 5) + j + t);
                    u[t] = (int)h2s[(size_t)sj * 32 + hl];
                }
#pragma unroll
                for (int t = 0; t < 8; ++t) {
                    alo[t] += __builtin_amdgcn_cvt_f32_fp8(u[t], 0);
                    ahi[t] += __builtin_amdgcn_cvt_f32_fp8(u[t], 1);
                }
            }
        }
    }
    float slo = ((alo[0] + alo[1]) + (alo[2] + alo[3])) + ((alo[4] + alo[5]) + (alo[6] + alo[7]));
    float shi = ((ahi[0] + ahi[1]) + (ahi[2] + ahi[3])) + ((ahi[4] + ahi[5]) + (ahi[6] + ahi[7]));

    float di = 1.0f / fmaxf((float)degr, 1.0f);
    float vlo = slo * di, vhi = shi * di;

    float m = fmaxf(vlo, vhi);
#pragma unroll
    for (int off = 16; off >= 1; off >>= 1)
        m = fmaxf(m, __shfl_xor(m, off));     // stays within the 32-lane half
    float e = expf(vlo - m) + expf(vhi - m);
#pragma unroll
    for (int off = 16; off >= 1; off >>= 1)
        e += __shfl_xor(e, off);
    float ls = logf(e);

    const int f_lo = ((hl >> 4) << 5) + (hl & 15);
    out[(size_t)node * OUT_F + f_lo]      = vlo - m - ls;
    out[(size_t)node * OUT_F + f_lo + 16] = vhi - m - ls;
}

// ---------------------------------------------------------------------------
extern "C" void kernel_launch(void* const* d_in, const int* in_sizes, int n_in,
                              void* d_out, int out_size, void* d_ws, size_t ws_size,
                              hipStream_t stream)
{
    const float* x  = (const float*)d_in[0];
    const int*   ei = (const int*)d_in[1];
    const float* w1 = (const float*)d_in[2];
    const float* b1 = (const float*)d_in[3];
    const float* c1 = (const float*)d_in[4];
    const float* w2 = (const float*)d_in[5];
    const float* b2 = (const float*)d_in[6];
    const float* c2 = (const float*)d_in[7];
    float* out = (float*)d_out;

    const int* src = ei;            // edge_index[0]
    const int* tgt = ei + N_EDGES;  // edge_index[1]

    char* ws = (char*)d_ws;
    size_t off = 0;
    auto carve = [&](size_t bytes) -> void* {
        void* p = ws + off;
        off = (off + bytes + 255) & ~(size_t)255;
        return p;
    };
    short*    Wb1       = (short*)carve((size_t)K_TOT * HID_F * 2);
    short*    Wb2       = (short*)carve((size_t)K_TOT * OUT_F * 2);
    int*      deg       = (int*)carve((size_t)N_NODES * 4);
    int*      prow      = (int*)carve((size_t)N_NODES * 4);
    int*      bcur      = (int*)carve((size_t)NBUCK * 4);
    unsigned* spk       = (unsigned*)carve((size_t)NBUCK * BCAP * 4);
    int*      csr_pad   = (int*)carve((size_t)NBUCK * PCAP * 4);
    unsigned* h1d       = (unsigned*)carve(((size_t)N_NODES + 1) * 128);  // fp8, permuted
    unsigned* a1d       = (unsigned*)carve((size_t)N_NODES * 128);        // fp8, permuted
    unsigned short* h2s = (unsigned short*)carve(((size_t)N_NODES + 1) * 64); // fp8 pairs

    // --- weights + sentinel rows + bucket cursor init ------------------------
    fold_weights_bf16<<<(K_TOT * HID_F + K_TOT * OUT_F + 255) / 256, 256, 0, stream>>>(
        w1, c1, w2, c2, Wb1, Wb2, h1d, (unsigned*)h2s, bcur);

    // --- bucket scatter ∥ kan1 part A ----------------------------------------
    scatter_kan1<<<NBLK_SORT + K1A, 256, 0, stream>>>(
        src, tgt, bcur, spk, x, Wb1, b1, h1d);

    // --- CSR finalize ∥ kan1 part B ------------------------------------------
    csr_kan1<<<NBUCK + K1B, 256, 0, stream>>>(
        bcur, spk, deg, prow, csr_pad, x, Wb1, b1, h1d);

    // --- aggregate 1 (gather, fp8 rows, 2 nodes/wave) ------------------------
    gather128<<<(N_NODES + 7) / 8, 256, 0, stream>>>(h1d, prow, deg, csr_pad, a1d);

    // --- layer 2 (fp8 in, fp8 out) -------------------------------------------
    kan2_mfma<<<(N_NODES + 63) / 64, 256, 0, stream>>>(a1d, deg, Wb2, b2, h2s);

    // --- aggregate 2 + log_softmax (fused, 2 nodes/wave, fp8) ----------------
    gather64_lsm<<<(N_NODES + 7) / 8, 256, 0, stream>>>(
        h2s, deg, prow, csr_pad, out);
}